// Round 13
// baseline (129.955 us; speedup 1.0000x reference)
//
#include <hip/hip_runtime.h>
#include <hip/hip_bf16.h>

#define NL    64
#define DIN   512
#define DOUT  512
#define BATCH 1024

#define BM 128
#define BN 128
#define BK 32
#define NKS (DIN / BK)   // 16

typedef short short8 __attribute__((ext_vector_type(8)));
typedef float f32x4  __attribute__((ext_vector_type(4)));

__device__ __forceinline__ unsigned int pk2(float a, float b) {
    // v_cvt_pk_bf16_f32 (RNE)
    __hip_bfloat162 h = __float22bfloat162_rn(make_float2(a, b));
    unsigned int r;
    __builtin_memcpy(&r, &h, 4);
    return r;
}

// ---- pre-pass: w fp32 [l][k][c] -> bf16 wt [l][c][k], swizzled ----
// Layout: per col, 16 chunks of 32 k (64 B). Within a chunk, 4 slots of
// 8 bf16; logical slot s stored at s ^ (c & 3).
__global__ __launch_bounds__(256) void wcvt_kernel(
        const float* __restrict__ w, unsigned short* __restrict__ wt) {
    __shared__ float T[64][65];
    const int tid = threadIdx.x;
    const int b   = blockIdx.x;
    const int l   = b >> 6;
    const int kg  = (b >> 3) & 7;   // 64-k group
    const int cg  = b & 7;          // 64-col group

    const float* src = w + ((size_t)(l * DIN) + kg * 64) * DOUT + cg * 64;
    const int j0 = (tid & 15) * 4;
    const int i0 = tid >> 4;
#pragma unroll
    for (int p = 0; p < 4; ++p) {
        const int i = p * 16 + i0;
        f32x4 v = *reinterpret_cast<const f32x4*>(src + (size_t)i * DOUT + j0);
        T[i][j0] = v[0]; T[i][j0 + 1] = v[1];
        T[i][j0 + 2] = v[2]; T[i][j0 + 3] = v[3];
    }
    __syncthreads();

    const int cl   = tid >> 2;      // 0..63
    const int part = tid & 3;       // 16 k each (half a 32-chunk)
    const int col  = cg * 64 + cl;
    float v[16];
#pragma unroll
    for (int q = 0; q < 16; ++q) v[q] = T[part * 16 + q][cl];
    uint4 u0, u1;
    u0.x = pk2(v[0], v[1]);  u0.y = pk2(v[2], v[3]);
    u0.z = pk2(v[4], v[5]);  u0.w = pk2(v[6], v[7]);
    u1.x = pk2(v[8], v[9]);  u1.y = pk2(v[10], v[11]);
    u1.z = pk2(v[12], v[13]); u1.w = pk2(v[14], v[15]);
    unsigned short* ob = wt + ((size_t)(l * DOUT) + col) * DIN
                       + kg * 64 + (part >> 1) * 32;
    const int key = col & 3;
    const int s0  = (part & 1) * 2;
    *reinterpret_cast<uint4*>(ob + ((s0       ^ key) << 3)) = u0;
    *reinterpret_cast<uint4*>(ob + (((s0 + 1) ^ key) << 3)) = u1;
}

// ---- GEMM: gload_lds double-buffered, counted drain, BK=32 ----
__global__ __launch_bounds__(256, 3) void nlinear_gemm(
        const float* __restrict__ x, const unsigned short* __restrict__ wt,
        const float* __restrict__ bias, float* __restrict__ out) {
    // A: fp32 [128][32] per buf (128B rows, 8 slots), read key = row&7,
    //    source pre-swizzled. B: bf16 [128][32] (64B rows, 4 slots),
    //    key = col&3, wt pre-swizzled in memory.
    __shared__ float          As[2][BM * BK];   // 2 x 16 KB
    __shared__ unsigned short Bs[2][BN * BK];   // 2 x 8 KB

    const int tid = threadIdx.x;
    const int bid = blockIdx.x;
    // XCD swizzle: 2048 = 8 XCDs x 256 blocks; each XCD owns 8 whole layers
    const int nb    = (bid & 7) * 256 + (bid >> 3);
    const int layer = nb >> 5;
    const int tile  = nb & 31;
    const int bm0   = (tile >> 2) * BM;
    const int bn0   = (tile & 3) * BN;

    const int wid  = tid >> 6;
    const int lane = tid & 63;
    const int wr   = wid >> 1, wc = wid & 1;   // 2x2 waves, 64x64 each
    const int lrow = lane & 15;
    const int lkb  = lane >> 4;

    // A staging: instr i -> rows i*32 + (tid>>3); slot tid&7 (16B fp32)
    const int arow  = tid >> 3;
    const int aoff  = ((tid & 7) ^ (arow & 7)) << 2;   // swizzled src float-offset
    // B staging: instr i -> cols i*64 + (tid>>2); slot tid&3 (16B bf16), linear src
    const int bcol  = tid >> 2;
    const int boff  = (tid & 3) * 8;

    const size_t XS = (size_t)NL * DIN;
    const float* xb = x + (size_t)bm0 * XS + (size_t)layer * DIN;
    const float* asrc0 = xb + (size_t)arow * XS + aoff;
    const unsigned short* bsrc0 =
        wt + ((size_t)(layer * DOUT) + bn0 + bcol) * DIN + boff;

    f32x4 acc[4][4];
#pragma unroll
    for (int i = 0; i < 4; ++i)
#pragma unroll
        for (int j = 0; j < 4; ++j) acc[i][j] = (f32x4){0.f, 0.f, 0.f, 0.f};

    auto stage = [&](int t, int db) {
#pragma unroll
        for (int i = 0; i < 4; ++i) {
            const float* g = asrc0 + (size_t)(i * 32) * XS + t * BK;
            __builtin_amdgcn_global_load_lds(
                (const __attribute__((address_space(1))) unsigned int*)g,
                (__attribute__((address_space(3))) unsigned int*)
                    ((char*)&As[db][0] + i * 4096 + tid * 16),
                16, 0, 0);
        }
#pragma unroll
        for (int i = 0; i < 2; ++i) {
            const unsigned short* g = bsrc0 + (size_t)(i * 64) * DIN + t * BK;
            __builtin_amdgcn_global_load_lds(
                (const __attribute__((address_space(1))) unsigned int*)g,
                (__attribute__((address_space(3))) unsigned int*)
                    ((char*)&Bs[db][0] + i * 4096 + tid * 16),
                16, 0, 0);
        }
    };

    // ---- prologue ----
    stage(0, 0);
    asm volatile("s_waitcnt vmcnt(0)" ::: "memory");
    __builtin_amdgcn_sched_barrier(0);
    __builtin_amdgcn_s_barrier();

#pragma unroll 1
    for (int t = 0; t < NKS; ++t) {
        const int db = t & 1;
        if (t + 1 < NKS) stage(t + 1, db ^ 1);   // loads fly under compute

        short8 af[4], bf[4];
#pragma unroll
        for (int mi = 0; mi < 4; ++mi) {
            const int row = wr * 64 + mi * 16 + lrow;
            const int key = row & 7;
            const float* rp = &As[db][row * BK];
            f32x4 v0 = *reinterpret_cast<const f32x4*>(
                rp + (((2 * lkb) ^ key) << 2));
            f32x4 v1 = *reinterpret_cast<const f32x4*>(
                rp + (((2 * lkb + 1) ^ key) << 2));
            uint4 u;
            u.x = pk2(v0[0], v0[1]); u.y = pk2(v0[2], v0[3]);
            u.z = pk2(v1[0], v1[1]); u.w = pk2(v1[2], v1[3]);
            __builtin_memcpy(&af[mi], &u, 16);
        }
#pragma unroll
        for (int ni = 0; ni < 4; ++ni) {
            const int col = wc * 64 + ni * 16 + lrow;
            bf[ni] = *reinterpret_cast<const short8*>(
                &Bs[db][col * BK + ((lkb ^ (col & 3)) << 3)]);
        }
        asm volatile("s_waitcnt lgkmcnt(0)" ::: "memory");
        __builtin_amdgcn_sched_barrier(0);

#pragma unroll
        for (int mi = 0; mi < 4; ++mi)
#pragma unroll
            for (int ni = 0; ni < 4; ++ni)
                acc[mi][ni] = __builtin_amdgcn_mfma_f32_16x16x32_bf16(
                    af[mi], bf[ni], acc[mi][ni], 0, 0, 0);

        // counted drain: stage(t+1) had the whole compute phase as cover
        if (t + 1 < NKS)
            asm volatile("s_waitcnt vmcnt(0)" ::: "memory");
        __builtin_amdgcn_sched_barrier(0);
        __builtin_amdgcn_s_barrier();
        __builtin_amdgcn_sched_barrier(0);
    }

    // ---- epilogue: + bias, fp32 store ----
    const float* bb = bias + (size_t)layer * DOUT + bn0;
    float* ob = out + (size_t)bm0 * (NL * DOUT) + (size_t)layer * DOUT + bn0;
#pragma unroll
    for (int mi = 0; mi < 4; ++mi) {
#pragma unroll
        for (int ni = 0; ni < 4; ++ni) {
            const int col = wc * 64 + ni * 16 + lrow;
            const float bval = bb[col];
#pragma unroll
            for (int r = 0; r < 4; ++r) {
                const int row = wr * 64 + mi * 16 + lkb * 4 + r;
                ob[(size_t)row * (NL * DOUT) + col] = acc[mi][ni][r] + bval;
            }
        }
    }
}

extern "C" void kernel_launch(void* const* d_in, const int* in_sizes, int n_in,
                              void* d_out, int out_size, void* d_ws, size_t ws_size,
                              hipStream_t stream) {
    const float* x  = (const float*)d_in[0];
    const float* w  = (const float*)d_in[1];
    const float* b  = (const float*)d_in[2];
    float* out      = (float*)d_out;
    unsigned short* wt = (unsigned short*)d_ws;   // 64*512*512*2 = 33.5 MB

    hipLaunchKernelGGL(wcvt_kernel, dim3(NL * 8 * 8), dim3(256), 0, stream, w, wt);
    hipLaunchKernelGGL(nlinear_gemm, dim3(NL * (BATCH / BM) * (DOUT / BN)),
                       dim3(256), 0, stream, x, wt, b, out);
}

// Round 14
// 93.845 us; speedup vs baseline: 1.3848x; 1.3848x over previous
//
#include <hip/hip_runtime.h>
#include <hip/hip_bf16.h>

#define NL    64
#define DIN   512
#define DOUT  512
#define BATCH 1024

#define BM 256
#define BN 256
#define BK 32
#define NK (DIN / BK)   // 16
#define LDSS 40         // padded row stride in shorts (80 B)

typedef short short8 __attribute__((ext_vector_type(8)));
typedef float f32x4  __attribute__((ext_vector_type(4)));

__device__ __forceinline__ unsigned int pk2(float a, float b) {
    // v_cvt_pk_bf16_f32 (RNE)
    __hip_bfloat162 h = __float22bfloat162_rn(make_float2(a, b));
    unsigned int r;
    __builtin_memcpy(&r, &h, 4);
    return r;
}

__global__ __launch_bounds__(512, 2) void nlinear_kernel(
        const float* __restrict__ x, const float* __restrict__ w,
        const float* __restrict__ bias, float* __restrict__ out) {
    // Double-buffered bf16 tiles [row][k], stride 40 shorts (80 B).
    // A: plain pad layout. B: 8B-slot XOR swizzle: quad q of col c at
    // slot q ^ ((c>>2)&7).
    __shared__ unsigned short As[2][BM * LDSS];   // 2 x 20 KB
    __shared__ unsigned short Bs[2][BN * LDSS];   // 2 x 20 KB

    const int tid = threadIdx.x;
    const int bid = blockIdx.x;
    // XCD swizzle: 512 blocks = 8 XCDs x 64; each XCD owns 8 whole layers.
    const int nb    = (bid & 7) * 64 + (bid >> 3);
    const int layer = nb >> 3;
    const int t8    = nb & 7;
    const int bm0   = (t8 & 3) * BM;
    const int bn0   = (t8 >> 2) * BN;

    const int wid  = tid >> 6;
    const int lane = tid & 63;
    const int wr   = wid >> 2, wc = wid & 3;   // 2M x 4N waves, 128x64 each
    const int lrow = lane & 15;
    const int lkb  = lane >> 4;                // k-octet 0..3

    // A-stage: 8 lanes/row (ak*4 floats), rows ar + 64p
    const int ar = tid >> 3;            // 0..63
    const int ak = tid & 7;
    // B-stage: wave gw owns k-quad gw; lane gc owns 4 cols
    const int gw = tid >> 6;            // 0..7
    const int gc = tid & 63;            // 0..63

    const size_t XS = (size_t)NL * DIN;
    const float* xb = x + (size_t)bm0 * XS + (size_t)layer * DIN;
    const float* wb = w + (size_t)layer * DIN * DOUT + bn0;
    const float* aptr0 = xb + (size_t)ar * XS + ak * 4;
    const float* bptr0 = wb + (size_t)(gw * 4) * DOUT + gc * 4;

    f32x4 acc[8][4];
#pragma unroll
    for (int i = 0; i < 8; ++i)
#pragma unroll
        for (int j = 0; j < 4; ++j) acc[i][j] = (f32x4){0.f, 0.f, 0.f, 0.f};

    f32x4 avE[4], avO[4];   // A ping-pong flight sets (2 intervals deep)
    f32x4 bv[4];            // B flight (1 interval)

    auto issueA = [&](int kt, f32x4 (&s)[4]) {
#pragma unroll
        for (int p = 0; p < 4; ++p)
            s[p] = *reinterpret_cast<const f32x4*>(
                aptr0 + (size_t)(64 * p) * XS + kt * BK);
    };
    auto issueB = [&](int kt) {
#pragma unroll
        for (int p = 0; p < 4; ++p)
            bv[p] = *reinterpret_cast<const f32x4*>(
                bptr0 + (size_t)(kt * BK + p) * DOUT);
    };

    auto cvtwriteA = [&](int db, f32x4 (&s)[4]) {
#pragma unroll
        for (int p = 0; p < 4; ++p) {
            uint2 wv;
            wv.x = pk2(s[p][0], s[p][1]);
            wv.y = pk2(s[p][2], s[p][3]);
            *reinterpret_cast<uint2*>(
                &As[db][(ar + 64 * p) * LDSS + ak * 4]) = wv;
        }
    };
    auto cvtwriteB = [&](int db) {
#pragma unroll
        for (int j = 0; j < 4; ++j) {
            const int c = gc * 4 + j;
            uint2 wv;
            wv.x = pk2(bv[0][j], bv[1][j]);
            wv.y = pk2(bv[2][j], bv[3][j]);
            const int slot = gw ^ ((c >> 2) & 7);
            *reinterpret_cast<uint2*>(
                &Bs[db][c * LDSS + slot * 4]) = wv;
        }
    };

    auto fragA = [&](int db, short8* af) {
#pragma unroll
        for (int mi = 0; mi < 8; ++mi) {
            const int row = wr * 128 + mi * 16 + lrow;
            af[mi] = *reinterpret_cast<const short8*>(
                &As[db][row * LDSS + lkb * 8]);
        }
    };
    auto fragB = [&](int db, short8* bf) {
#pragma unroll
        for (int ni = 0; ni < 4; ++ni) {
            const int col = wc * 64 + ni * 16 + lrow;
            const int key = (col >> 2) & 7;
            const unsigned short* base = &Bs[db][col * LDSS];
            uint2 lo = *reinterpret_cast<const uint2*>(
                base + (((2 * lkb) ^ key) << 2));
            uint2 hi = *reinterpret_cast<const uint2*>(
                base + (((2 * lkb + 1) ^ key) << 2));
            uint4 u = make_uint4(lo.x, lo.y, hi.x, hi.y);
            __builtin_memcpy(&bf[ni], &u, 16);
        }
    };

#define BARRIER() do { \
        asm volatile("s_waitcnt lgkmcnt(0)" ::: "memory"); \
        __builtin_amdgcn_sched_barrier(0); \
        __builtin_amdgcn_s_barrier(); \
        __builtin_amdgcn_sched_barrier(0); } while (0)

// T14 ordering: frag reads -> lgkm wait -> MFMA cluster (clean), staging after.
#define COMPUTE(DB, AF, BF) do { \
        fragA(DB, AF); \
        fragB(DB, BF); \
        asm volatile("s_waitcnt lgkmcnt(0)" ::: "memory"); \
        __builtin_amdgcn_sched_barrier(0); \
        __builtin_amdgcn_s_setprio(1); \
        _Pragma("unroll") \
        for (int mi = 0; mi < 8; ++mi) \
        _Pragma("unroll") \
            for (int ni = 0; ni < 4; ++ni) \
                acc[mi][ni] = __builtin_amdgcn_mfma_f32_16x16x32_bf16( \
                    AF[mi], BF[ni], acc[mi][ni], 0, 0, 0); \
        __builtin_amdgcn_s_setprio(0); \
        __builtin_amdgcn_sched_barrier(0); } while (0)

    // ---- prologue ----
    issueA(0, avE);         // tile0 -> E
    issueB(0);
    cvtwriteA(0, avE);      // stalls on A(0) once
    cvtwriteB(0);
    issueA(1, avO);         // tile1 -> O
    issueB(1);
    issueA(2, avE);         // tile2 -> E (2 intervals ahead)
    BARRIER();

    // ---- steady state: 2-step unrolled; staging AFTER the MFMA cluster ----
#pragma unroll 1
    for (int k = 0; k < NK - 2; k += 2) {
        {   // step A: compute tile k (buf0); then stage k+1 from avO
            short8 af[8], bf[4];
            COMPUTE(0, af, bf);
            cvtwriteA(1, avO);           // vmcnt waits here, post-MFMA
            cvtwriteB(1);
            issueA(k + 3, avO);          // k<=12 -> k+3<=15, always valid
            issueB(k + 2);
            BARRIER();
        }
        {   // step B: compute tile k+1 (buf1); then stage k+2 from avE
            short8 af[8], bf[4];
            COMPUTE(1, af, bf);
            cvtwriteA(0, avE);
            cvtwriteB(0);
            if (k + 4 < NK) issueA(k + 4, avE);
            issueB(k + 3);
            BARRIER();
        }
    }
    // ---- k = NK-2 (buf0): compute, then stage last tile (NK-1) ----
    {
        short8 af[8], bf[4];
        COMPUTE(0, af, bf);
        cvtwriteA(1, avO);
        cvtwriteB(1);
        BARRIER();
    }
    // ---- k = NK-1 (buf1): compute only ----
    {
        short8 af[8], bf[4];
        COMPUTE(1, af, bf);
    }

    // ---- epilogue: + bias, fp32 store ----
    const float* bb = bias + (size_t)layer * DOUT + bn0;
    float* ob = out + (size_t)bm0 * (NL * DOUT) + (size_t)layer * DOUT + bn0;
#pragma unroll
    for (int mi = 0; mi < 8; ++mi) {
#pragma unroll
        for (int ni = 0; ni < 4; ++ni) {
            const int col = wc * 64 + ni * 16 + lrow;
            const float bval = bb[col];
#pragma unroll
            for (int r = 0; r < 4; ++r) {
                const int row = wr * 128 + mi * 16 + lkb * 4 + r;
                ob[(size_t)row * (NL * DOUT) + col] = acc[mi][ni][r] + bval;
            }
        }
    }
#undef BARRIER
#undef COMPUTE
}

extern "C" void kernel_launch(void* const* d_in, const int* in_sizes, int n_in,
                              void* d_out, int out_size, void* d_ws, size_t ws_size,
                              hipStream_t stream) {
    const float* x  = (const float*)d_in[0];
    const float* w  = (const float*)d_in[1];
    const float* b  = (const float*)d_in[2];
    float* out      = (float*)d_out;

    dim3 grid(NL * (BATCH / BM) * (DOUT / BN));   // 64 * 4 * 2 = 512
    dim3 block(512);
    hipLaunchKernelGGL(nlinear_kernel, grid, block, 0, stream, x, w, b, out);
}